// Round 5
// baseline (346.564 us; speedup 1.0000x reference)
//
#include <hip/hip_runtime.h>
#include <cmath>

constexpr int Bn = 512, Cn = 256, Tn = 256, En = 8;
constexpr float EPSf = 1e-5f;

using bf16x8 = __attribute__((ext_vector_type(8))) short;
using f32x4  = __attribute__((ext_vector_type(4))) float;

__device__ __forceinline__ ushort f2bf(float f) {
    uint u = __builtin_bit_cast(uint, f);
    uint r = u + 0x7FFFu + ((u >> 16) & 1u);   // RNE
    return (ushort)(r >> 16);
}
__device__ __forceinline__ float bf2f(ushort u) {
    uint v = (uint)u << 16;
    return __builtin_bit_cast(float, v);
}

// Pre-kernel: W fp32 [E][co][ci][K] -> Wws bf16 [E][k][co][ci]
__global__ __launch_bounds__(256)
void wconv_kernel(const float* __restrict__ Wf, ushort* __restrict__ Wws) {
    int idx = blockIdx.x * 256 + threadIdx.x;   // e*65536 + co*256 + ci
    const float* src = Wf + (size_t)idx * 5;
    int ci = idx & 255, co = (idx >> 8) & 255, e = idx >> 16;
#pragma unroll
    for (int k = 0; k < 5; ++k)
        Wws[(((size_t)(e * 5 + k) * 256 + co) << 8) + ci] = f2bf(src[k]);
}

// Conv: logical block = (b, t-quarter); XCD-chunk swizzle keeps the 4 sibling
// t-quarters of one sample on ONE XCD (shared L2 -> x fetched once from HBM).
// 256 thr = 4 waves; wave w: co [w*64,+64) x t [tb,tb+64), 4x4 16x16x32 frags.
// LDS xT double-buffered [2][68][40] ushort (t' = t-tb+2, halo +-2).
// Pipeline: {WRITE(t+1 -> buf^1); LOAD(t+2); MFMA(buf); barrier} - 1 barrier/tile.
template<bool YBF16, bool WS_W>
__global__ __launch_bounds__(256, 4)
void conv_mfma(const float* __restrict__ x, const int* __restrict__ expert,
               const float* __restrict__ Wf, const ushort* __restrict__ Wws,
               const float* __restrict__ bias,
               float* __restrict__ partial,   // [B][4][8][2]
               void* __restrict__ yout)       // bf16 (ws) or fp32 (out)
{
    const int id = blockIdx.x;
    const int wg = (id & 7) * 256 + (id >> 3);   // XCD-chunk swizzle (2048=8*256)
    const int b  = wg >> 2, tq = wg & 3;
    const int tb = tq * 64;
    const int e  = __builtin_amdgcn_readfirstlane(expert[b]);
    const int tid = threadIdx.x;
    const int w = tid >> 6, l = tid & 63, q = l >> 4, r = l & 15;

    __shared__ ushort xT[2][68 * 40];

    f32x4 acc[4][4];
#pragma unroll
    for (int m = 0; m < 4; ++m)
#pragma unroll
        for (int n = 0; n < 4; ++n) acc[m][n] = f32x4{0.f, 0.f, 0.f, 0.f};

    // staging: lane l -> row t' = l (t = tb-2+l); lanes 0..3 also rows 64..67
    const int t1 = tb - 2 + l;
    const bool ok1 = (t1 >= 0) && (t1 < Tn);
    const int t2 = tb + 62 + l;
    const bool ok2 = (l < 4) && (t2 < Tn);
    float v[8], vh[8];

#define STAGE_LOAD(CI0) {                                                    \
        const float* xb = x + ((size_t)b * Cn + (CI0) + w * 8) * Tn;         \
        _Pragma("unroll")                                                    \
        for (int rr = 0; rr < 8; ++rr) v[rr]  = ok1 ? xb[rr * Tn + t1] : 0.f;\
        _Pragma("unroll")                                                    \
        for (int rr = 0; rr < 8; ++rr) vh[rr] = ok2 ? xb[rr * Tn + t2] : 0.f;\
    }
#define STAGE_WRITE(BUF) {                                                   \
        ushort* xb_ = xT[BUF];                                               \
        uint p0 = (uint)f2bf(v[0]) | ((uint)f2bf(v[1]) << 16);               \
        uint p1 = (uint)f2bf(v[2]) | ((uint)f2bf(v[3]) << 16);               \
        uint p2 = (uint)f2bf(v[4]) | ((uint)f2bf(v[5]) << 16);               \
        uint p3 = (uint)f2bf(v[6]) | ((uint)f2bf(v[7]) << 16);               \
        *reinterpret_cast<uint2*>(&xb_[l * 40 + w * 8])     = make_uint2(p0, p1);\
        *reinterpret_cast<uint2*>(&xb_[l * 40 + w * 8 + 4]) = make_uint2(p2, p3);\
        if (l < 4) {                                                         \
            uint h0 = (uint)f2bf(vh[0]) | ((uint)f2bf(vh[1]) << 16);         \
            uint h1 = (uint)f2bf(vh[2]) | ((uint)f2bf(vh[3]) << 16);         \
            uint h2 = (uint)f2bf(vh[4]) | ((uint)f2bf(vh[5]) << 16);         \
            uint h3 = (uint)f2bf(vh[6]) | ((uint)f2bf(vh[7]) << 16);         \
            *reinterpret_cast<uint2*>(&xb_[(64 + l) * 40 + w * 8])     = make_uint2(h0, h1);\
            *reinterpret_cast<uint2*>(&xb_[(64 + l) * 40 + w * 8 + 4]) = make_uint2(h2, h3);\
        }                                                                    \
    }

    STAGE_LOAD(0);
    STAGE_WRITE(0);
    STAGE_LOAD(32);
    __syncthreads();

#pragma unroll 1
    for (int ct = 0; ct < 8; ++ct) {
        // write tile ct+1 into buf (ct+1)&1: its last reader (MFMA ct-1)
        // finished before the barrier that ended iteration ct-1.
        if (ct < 7) {
            STAGE_WRITE((ct + 1) & 1);
            if (ct < 6) STAGE_LOAD((ct + 2) * 32);  // 2-tile lookahead
        }
        const int ci0 = ct * 32;
        const ushort* xb_ = xT[ct & 1];

#pragma unroll
        for (int k = 0; k < 5; ++k) {
            bf16x8 A[4];
#pragma unroll
            for (int m = 0; m < 4; ++m) {
                if (WS_W) {
                    A[m] = *reinterpret_cast<const bf16x8*>(
                        Wws + (((size_t)((e * 5 + k) * 256 + w * 64 + m * 16 + r)) << 8)
                            + ci0 + q * 8);
                } else {
                    bf16x8 a;
#pragma unroll
                    for (int j = 0; j < 8; ++j)
                        a[j] = (short)f2bf(
                            Wf[((size_t)(e * 256 + w * 64 + m * 16 + r) * 256
                                + ci0 + q * 8 + j) * 5 + k]);
                    A[m] = a;
                }
            }
#pragma unroll
            for (int n = 0; n < 4; ++n) {
                const bf16x8 Bf = *reinterpret_cast<const bf16x8*>(
                    &xb_[(n * 16 + r + k) * 40 + q * 8]);
#pragma unroll
                for (int m = 0; m < 4; ++m)
                    acc[m][n] = __builtin_amdgcn_mfma_f32_16x16x32_bf16(
                        A[m], Bf, acc[m][n], 0, 0, 0);
            }
        }
        __syncthreads();
    }
#undef STAGE_LOAD
#undef STAGE_WRITE

    // ---- bias + partial group stats (wave w: groups 2w [m<2], 2w+1 [m>=2]) ----
    float s1[2] = {0.f, 0.f}, s2[2] = {0.f, 0.f};
#pragma unroll
    for (int m = 0; m < 4; ++m) {
        const int gi = m >> 1;
#pragma unroll
        for (int i = 0; i < 4; ++i) {
            const float bv = bias[e * Cn + w * 64 + m * 16 + q * 4 + i];
#pragma unroll
            for (int n = 0; n < 4; ++n) {
                const float val = acc[m][n][i] + bv;
                acc[m][n][i] = val;
                s1[gi] += val;
                s2[gi] += val * val;
            }
        }
    }
#pragma unroll
    for (int off = 32; off; off >>= 1) {
        s1[0] += __shfl_xor(s1[0], off); s2[0] += __shfl_xor(s2[0], off);
        s1[1] += __shfl_xor(s1[1], off); s2[1] += __shfl_xor(s2[1], off);
    }
    if (l == 0) {
        float* p = partial + ((size_t)(b * 4 + tq) * 8 + w * 2) * 2;
        p[0] = s1[0]; p[1] = s2[0]; p[2] = s1[1]; p[3] = s2[1];
    }

    // ---- store y (conv + bias) ----
#pragma unroll
    for (int m = 0; m < 4; ++m) {
#pragma unroll
        for (int i = 0; i < 4; ++i) {
            const int co = w * 64 + m * 16 + q * 4 + i;
            const size_t base = ((size_t)(b * Cn + co)) * Tn + tb + r;
#pragma unroll
            for (int n = 0; n < 4; ++n) {
                if (YBF16)
                    ((ushort*)yout)[base + n * 16] = f2bf(acc[m][n][i]);
                else
                    ((float*)yout)[base + n * 16] = acc[m][n][i];
            }
        }
    }
}

// Reduce: 4 t-quarter partials -> mu, rstd per (b, g). 4096 threads.
__global__ __launch_bounds__(256)
void stats_reduce(const float* __restrict__ partial, float* __restrict__ stats) {
    const int t = blockIdx.x * 256 + threadIdx.x;   // [0, 4096)
    const int b = t >> 3, g = t & 7;
    float s1 = 0.f, s2 = 0.f;
#pragma unroll
    for (int tq = 0; tq < 4; ++tq) {
        const float* p = partial + ((size_t)(b * 4 + tq) * 8 + g) * 2;
        s1 += p[0]; s2 += p[1];
    }
    constexpr float invn = 1.0f / (32 * 256);
    const float mu  = s1 * invn;
    const float var = fmaf(-mu, mu, s2 * invn);
    stats[t * 2]     = mu;
    stats[t * 2 + 1] = rsqrtf(var + EPSf);
}

// Normalize + Mish: memory-bound, 8 elems/thread, 16384 blocks x 256.
template<bool YBF16>
__global__ __launch_bounds__(256)
void norm_mish(const void* __restrict__ yin, const int* __restrict__ expert,
               const float* __restrict__ stats,
               const float* __restrict__ gamma, const float* __restrict__ beta,
               float* __restrict__ out)
{
    const int idx = blockIdx.x * 256 + threadIdx.x;
    const int row = idx >> 5, seg = idx & 31;
    const int b = row >> 8, co = row & 255, g = co >> 5;
    const int e = expert[b];
    const float mu = stats[(b * 8 + g) * 2];
    const float rs = stats[(b * 8 + g) * 2 + 1];
    const float sc = gamma[e * Cn + co] * rs;
    const float sh = beta[e * Cn + co] - mu * sc;
    const size_t base = (size_t)row * Tn + seg * 8;

    float yv[8];
    if (YBF16) {
        const bf16x8 raw = *reinterpret_cast<const bf16x8*>((const ushort*)yin + base);
#pragma unroll
        for (int j = 0; j < 8; ++j) yv[j] = bf2f((ushort)raw[j]);
    } else {
        const float4 a = *reinterpret_cast<const float4*>((const float*)yin + base);
        const float4 c = *reinterpret_cast<const float4*>((const float*)yin + base + 4);
        yv[0] = a.x; yv[1] = a.y; yv[2] = a.z; yv[3] = a.w;
        yv[4] = c.x; yv[5] = c.y; yv[6] = c.z; yv[7] = c.w;
    }

    float o[8];
#pragma unroll
    for (int j = 0; j < 8; ++j) {
        const float y  = fmaf(yv[j], sc, sh);
        const float u  = __expf(y);
        const float t2 = u * (u + 2.f);
        o[j] = (y > 20.f) ? y : y * t2 / (t2 + 2.f);
    }
    float4 o0 = {o[0], o[1], o[2], o[3]};
    float4 o1 = {o[4], o[5], o[6], o[7]};
    *reinterpret_cast<float4*>(out + base)     = o0;
    *reinterpret_cast<float4*>(out + base + 4) = o1;
}

extern "C" void kernel_launch(void* const* d_in, const int* in_sizes, int n_in,
                              void* d_out, int out_size, void* d_ws, size_t ws_size,
                              hipStream_t stream) {
    const float* x      = (const float*)d_in[0];
    const int*   expert = (const int*)  d_in[1];
    const float* Wf     = (const float*)d_in[2];
    const float* bias   = (const float*)d_in[3];
    const float* gamma  = (const float*)d_in[4];
    const float* beta   = (const float*)d_in[5];
    float* out = (float*)d_out;

    const size_t WWS_BYTES  = (size_t)En * 5 * 256 * 256 * 2;     // 5,242,880
    const size_t PART_BYTES = (size_t)Bn * 4 * 8 * 2 * 4;         //   131,072
    const size_t STAT_BYTES = (size_t)Bn * 8 * 2 * 4;             //    32,768
    const size_t Y_BYTES    = (size_t)Bn * Cn * Tn * 2;           // 67,108,864

    const bool ws_w  = ws_size >= WWS_BYTES + PART_BYTES + STAT_BYTES;
    char* wsb = (char*)d_ws;

    ushort* Wws;
    float *partial, *stats;
    if (ws_w) {
        Wws     = (ushort*)wsb;
        partial = (float*)(wsb + WWS_BYTES);
        stats   = (float*)(wsb + WWS_BYTES + PART_BYTES);
    } else {
        Wws     = nullptr;
        partial = (float*)wsb;
        stats   = (float*)(wsb + PART_BYTES);
    }
    const size_t y_off = ws_w ? (WWS_BYTES + PART_BYTES + STAT_BYTES)
                              : (PART_BYTES + STAT_BYTES);
    const bool ybf = ws_size >= y_off + Y_BYTES;
    void* ybuf = ybf ? (void*)(wsb + y_off) : (void*)out;

    if (ws_w)
        hipLaunchKernelGGL(wconv_kernel, dim3(2048), dim3(256), 0, stream, Wf, Wws);

    if (ws_w && ybf)
        hipLaunchKernelGGL((conv_mfma<true, true>), dim3(2048), dim3(256), 0, stream,
                           x, expert, Wf, Wws, bias, partial, ybuf);
    else if (ws_w)
        hipLaunchKernelGGL((conv_mfma<false, true>), dim3(2048), dim3(256), 0, stream,
                           x, expert, Wf, Wws, bias, partial, ybuf);
    else
        hipLaunchKernelGGL((conv_mfma<false, false>), dim3(2048), dim3(256), 0, stream,
                           x, expert, Wf, nullptr, bias, partial, ybuf);

    hipLaunchKernelGGL(stats_reduce, dim3(16), dim3(256), 0, stream, partial, stats);

    if (ybf)
        hipLaunchKernelGGL((norm_mish<true>), dim3(16384), dim3(256), 0, stream,
                           ybuf, expert, stats, gamma, beta, out);
    else
        hipLaunchKernelGGL((norm_mish<false>), dim3(16384), dim3(256), 0, stream,
                           ybuf, expert, stats, gamma, beta, out);
}

// Round 6
// 218.208 us; speedup vs baseline: 1.5882x; 1.5882x over previous
//
#include <hip/hip_runtime.h>
#include <cmath>

constexpr int Bn = 512, Cn = 256, Tn = 256, En = 8;
constexpr float EPSf = 1e-5f;

using bf16x8 = __attribute__((ext_vector_type(8))) short;
using f32x4  = __attribute__((ext_vector_type(4))) float;

__device__ __forceinline__ ushort f2bf(float f) {
    uint u = __builtin_bit_cast(uint, f);
    uint r = u + 0x7FFFu + ((u >> 16) & 1u);   // RNE
    return (ushort)(r >> 16);
}

// Pre-kernel: W fp32 [E][co][ci][K] -> Wws bf16 [E][k][co][ci]
__global__ __launch_bounds__(256)
void wconv_kernel(const float* __restrict__ Wf, ushort* __restrict__ Wws) {
    int idx = blockIdx.x * 256 + threadIdx.x;   // e*65536 + co*256 + ci
    const float* src = Wf + (size_t)idx * 5;
    int ci = idx & 255, co = (idx >> 8) & 255, e = idx >> 16;
#pragma unroll
    for (int k = 0; k < 5; ++k)
        Wws[(((size_t)(e * 5 + k) * 256 + co) << 8) + ci] = f2bf(src[k]);
}

// Fused conv+GroupNorm+Mish. Block = (b, group-pair gp): co [gp*64,+64), all t.
// 2048 blocks x 256 thr (4 waves); wave w owns t-slice [w*64,+64).
// Per wave: 4m x 4n frags of 16x16x32 (acc 64 VGPR).
// LDS xT double-buffered [2][260][40] ushort (xT[t+2] = x[t], halo zeros).
// Pipeline: {WRITE(ct+1 -> buf^1); LOAD(ct+2); 20 A-loads; MFMA; barrier}.
template<bool WS_W>
__global__ __launch_bounds__(256, 2)
void conv_gn_mish(const float* __restrict__ x, const int* __restrict__ expert,
                  const float* __restrict__ Wf, const ushort* __restrict__ Wws,
                  const float* __restrict__ bias, const float* __restrict__ gamma,
                  const float* __restrict__ beta, float* __restrict__ out)
{
    const int id = blockIdx.x;
    const int wg = (id & 7) * 256 + (id >> 3);   // XCD-chunk swizzle (2048=8*256)
    const int b  = wg >> 2;
    const int gp = wg & 3;
    const int cb = gp * 64;
    const int e  = __builtin_amdgcn_readfirstlane(expert[b]);

    const int tid = threadIdx.x;
    const int w = tid >> 6, l = tid & 63, q = l >> 4, r = l & 15;

    __shared__ ushort xT[2][260 * 40];
    __shared__ float red[4][4];

    f32x4 acc[4][4];
#pragma unroll
    for (int m = 0; m < 4; ++m)
#pragma unroll
        for (int n = 0; n < 4; ++n) acc[m][n] = f32x4{0.f, 0.f, 0.f, 0.f};

    // zero halo rows (t' = 0,1,258,259) in BOTH buffers; never overwritten
    if (tid < 8) {
        const int bf = tid >> 2, rr = tid & 3;
        const int row = (rr < 2) ? rr : (256 + rr);
#pragma unroll
        for (int i = 0; i < 10; ++i)
            *reinterpret_cast<uint2*>(&xT[bf][row * 40 + i * 4]) = make_uint2(0u, 0u);
    }

    float v[4][8];   // staging: v[tt][rr] = x[ci0 + w*8 + rr][tt*64 + l]

#define STAGE_LOAD(CI0) {                                                    \
        const float* xb = x + ((size_t)b * Cn + (CI0) + w * 8) * Tn;         \
        _Pragma("unroll")                                                    \
        for (int tt = 0; tt < 4; ++tt) {                                     \
            const int t = tt * 64 + l;                                       \
            _Pragma("unroll")                                                \
            for (int rr = 0; rr < 8; ++rr) v[tt][rr] = xb[rr * Tn + t];      \
        }                                                                    \
    }
#define STAGE_WRITE(BUF) {                                                   \
        ushort* dst = xT[BUF];                                               \
        _Pragma("unroll")                                                    \
        for (int tt = 0; tt < 4; ++tt) {                                     \
            const int t = tt * 64 + l;                                       \
            uint p0 = (uint)f2bf(v[tt][0]) | ((uint)f2bf(v[tt][1]) << 16);   \
            uint p1 = (uint)f2bf(v[tt][2]) | ((uint)f2bf(v[tt][3]) << 16);   \
            uint p2 = (uint)f2bf(v[tt][4]) | ((uint)f2bf(v[tt][5]) << 16);   \
            uint p3 = (uint)f2bf(v[tt][6]) | ((uint)f2bf(v[tt][7]) << 16);   \
            *reinterpret_cast<uint2*>(&dst[(t + 2) * 40 + w * 8])     = make_uint2(p0, p1); \
            *reinterpret_cast<uint2*>(&dst[(t + 2) * 40 + w * 8 + 4]) = make_uint2(p2, p3); \
        }                                                                    \
    }

    STAGE_LOAD(0);
    STAGE_WRITE(0);
    STAGE_LOAD(32);
    __syncthreads();

#pragma unroll 1
    for (int ct = 0; ct < 8; ++ct) {
        if (ct < 7) {
            STAGE_WRITE((ct + 1) & 1);
            if (ct < 6) STAGE_LOAD((ct + 2) * 32);   // 2-tile lookahead
        }
        const int ci0 = ct * 32;
        const ushort* src = xT[ct & 1];

        // hoist ALL 20 A-frag loads for this tile (80 VGPRs in flight)
        bf16x8 A[5][4];
#pragma unroll
        for (int k = 0; k < 5; ++k) {
#pragma unroll
            for (int m = 0; m < 4; ++m) {
                if (WS_W) {
                    A[k][m] = *reinterpret_cast<const bf16x8*>(
                        Wws + (((size_t)((e * 5 + k) * 256 + cb + m * 16 + r)) << 8)
                            + ci0 + q * 8);
                } else {
                    bf16x8 a;
#pragma unroll
                    for (int j = 0; j < 8; ++j)
                        a[j] = (short)f2bf(
                            Wf[((size_t)(e * 256 + cb + m * 16 + r) * 256
                                + ci0 + q * 8 + j) * 5 + k]);
                    A[k][m] = a;
                }
            }
        }
#pragma unroll
        for (int k = 0; k < 5; ++k) {
#pragma unroll
            for (int n = 0; n < 4; ++n) {
                const bf16x8 Bf = *reinterpret_cast<const bf16x8*>(
                    &src[(w * 64 + n * 16 + r + k) * 40 + q * 8]);
#pragma unroll
                for (int m = 0; m < 4; ++m)
                    acc[m][n] = __builtin_amdgcn_mfma_f32_16x16x32_bf16(
                        A[k][m], Bf, acc[m][n], 0, 0, 0);
            }
        }
        __syncthreads();
    }
#undef STAGE_LOAD
#undef STAGE_WRITE

    // ---- bias + GroupNorm stats (group A: m 0,1 -> co cb..cb+31; B: m 2,3) ----
    float s1a = 0.f, s2a = 0.f, s1b = 0.f, s2b = 0.f;
#pragma unroll
    for (int m = 0; m < 4; ++m) {
#pragma unroll
        for (int i = 0; i < 4; ++i) {
            const float bv = bias[e * Cn + cb + m * 16 + q * 4 + i];
#pragma unroll
            for (int n = 0; n < 4; ++n) {
                const float val = acc[m][n][i] + bv;
                acc[m][n][i] = val;
                if (m < 2) { s1a += val; s2a += val * val; }
                else       { s1b += val; s2b += val * val; }
            }
        }
    }
#pragma unroll
    for (int off = 32; off; off >>= 1) {
        s1a += __shfl_xor(s1a, off); s2a += __shfl_xor(s2a, off);
        s1b += __shfl_xor(s1b, off); s2b += __shfl_xor(s2b, off);
    }
    if (l == 0) { red[w][0] = s1a; red[w][1] = s2a; red[w][2] = s1b; red[w][3] = s2b; }
    __syncthreads();
    const float S1a = red[0][0] + red[1][0] + red[2][0] + red[3][0];
    const float S2a = red[0][1] + red[1][1] + red[2][1] + red[3][1];
    const float S1b = red[0][2] + red[1][2] + red[2][2] + red[3][2];
    const float S2b = red[0][3] + red[1][3] + red[2][3] + red[3][3];

    constexpr float invn = 1.0f / (32 * 256);
    const float mua = S1a * invn, mub = S1b * invn;
    const float rsa = rsqrtf(fmaf(-mua, mua, S2a * invn) + EPSf);
    const float rsb = rsqrtf(fmaf(-mub, mub, S2b * invn) + EPSf);

    // ---- normalize + Mish + store ----
#pragma unroll
    for (int m = 0; m < 4; ++m) {
        const float mu = (m < 2) ? mua : mub;
        const float rs = (m < 2) ? rsa : rsb;
#pragma unroll
        for (int i = 0; i < 4; ++i) {
            const int co = cb + m * 16 + q * 4 + i;
            const float sc = gamma[e * Cn + co] * rs;
            const float sh = beta[e * Cn + co] - mu * sc;
            float* orow = out + ((size_t)(b * Cn + co)) * Tn + w * 64 + r;
#pragma unroll
            for (int n = 0; n < 4; ++n) {
                const float y = fmaf(acc[m][n][i], sc, sh);
                const float u  = __expf(y);
                const float t2 = u * (u + 2.f);
                const float ms = (y > 20.f) ? y : y * t2 / (t2 + 2.f);
                orow[n * 16] = ms;
            }
        }
    }
}

extern "C" void kernel_launch(void* const* d_in, const int* in_sizes, int n_in,
                              void* d_out, int out_size, void* d_ws, size_t ws_size,
                              hipStream_t stream) {
    const float* x      = (const float*)d_in[0];
    const int*   expert = (const int*)  d_in[1];
    const float* Wf     = (const float*)d_in[2];
    const float* bias   = (const float*)d_in[3];
    const float* gamma  = (const float*)d_in[4];
    const float* beta   = (const float*)d_in[5];
    float* out = (float*)d_out;

    const size_t WWS_BYTES = (size_t)En * 5 * 256 * 256 * 2;   // 5,242,880

    if (ws_size >= WWS_BYTES) {
        ushort* Wws = (ushort*)d_ws;
        hipLaunchKernelGGL(wconv_kernel, dim3(2048), dim3(256), 0, stream, Wf, Wws);
        hipLaunchKernelGGL((conv_gn_mish<true>), dim3(2048), dim3(256), 0, stream,
                           x, expert, Wf, Wws, bias, gamma, beta, out);
    } else {
        hipLaunchKernelGGL((conv_gn_mish<false>), dim3(2048), dim3(256), 0, stream,
                           x, expert, Wf, nullptr, bias, gamma, beta, out);
    }
}